// Round 21
// baseline (90.071 us; speedup 1.0000x reference)
//
#include <hip/hip_runtime.h>
#include <hip/hip_bf16.h>
#include <stdint.h>

// Fused NCA step via MATRIX CORES — bf16 dual-copy tile, bank-deconflicted.
// perception(4 fixed 3x3, wrap) -> 1x1 conv 32->16 +b+ReLU -> 1x1 conv 16->8
// -> x + y*mask.
// R21 = R20 with ONE class of change: LDS bank layout. R20's 7.36M bank
// conflicts came from copyO base 259 == 3 (mod 32): even-p lanes' banks
// (8w+3..10) overlapped odd-p lanes' (8w+0..7) -> 4-way on 5 banks.
// Now copyO[m] at 265+m (copyO[-1] at 264; 264 == 8 mod 16): even-p banks
// 8w+8..15, odd-p 8w+0..7 -> disjoint; group channel stride CH32 == 8
// (mod 32) puts groups {0,2}/{1,3} on complementary halves -> 2 lanes/bank
// everywhere = conflict-free (m136). copyO stage-writes become 2x b32
// (odd base). Everything else byte-identical to R20.

constexpr int B = 16, C = 8, H = 512, W = 512, HID = 16;
constexpr int HW = H * W;

// LDS (u32). Per (ch,row): copyE[m]=cols(2m,2m+1) at [0..256] (m=256 = halo
// cols 0,1); copyO[-1]=(511,0) at [264]; copyO[m]=cols(2m+1,2m+2) at [265+m]
// (m=0..255; m=255 wraps 512->0). ROW32=528 (%32=16), CH32%32=8.
constexpr int ROW32 = 528;
constexpr int CH32  = 4 * ROW32 + 8;     // 2120 per channel (4 rows)
constexpr int XTOT  = 8 * CH32;          // 16960
constexpr int MOFF  = XTOT;              // 2 mask rows (raw int bits)
constexpr int LDSU  = XTOT + 2 * 512;    // 17984 u32 = 71936 B

typedef __attribute__((ext_vector_type(8))) short bf16x8;
typedef __attribute__((ext_vector_type(4))) float f32x4;
typedef const __attribute__((address_space(1))) void* as1cp;
typedef __attribute__((address_space(3))) void* as3p;

__device__ __host__ inline uint32_t bf16rne(float f) {   // low 16 bits
    const uint32_t u = __float_as_uint(f);
    return (u + 0x7fffu + ((u >> 16) & 1u)) >> 16;
}
__device__ __host__ inline float bf16tof(uint32_t hs) {
    union { uint32_t u; float f; } c; c.u = hs << 16; return c.f;
}
// pack {bf16(a) low, bf16(b) high} via HW cvt_pk (RNE)
__device__ inline uint32_t pk2(float a, float b) {
    union { __hip_bfloat162 h; uint32_t u; } r;
    r.h = __float22bfloat162_rn(make_float2(a, b));
    return r.u;
}

// d_ws (u32): [q*512 .. q*512+255] chunk-q W1 hi frag, [+256..511] lo frag
// (q=0,1,2 <-> dy=-1,0,+1); [1536..1791] W2 frag; [1792..1807] bias f32.
__global__ void repack(const float* __restrict__ w1w,
                       const float* __restrict__ w1b,
                       const float* __restrict__ w2w,
                       float* __restrict__ wdf) {
    uint32_t* wd = (uint32_t*)wdf;
    const int t = threadIdx.x;
    if (t >= 64) return;
    const int h = t & 15, kg = t >> 4;
    const float SX[3][3] = {{-0.125f, 0.f, 0.125f},
                            {-0.25f,  0.f, 0.25f},
                            {-0.125f, 0.f, 0.125f}};
    const float LP[3][3] = {{0.0625f, 0.125f, 0.0625f},
                            {0.125f, -0.75f,  0.125f},
                            {0.0625f, 0.125f, 0.0625f}};
    for (int q = 0; q < 3; ++q) {         // dy = q-1
        uint32_t whi[4] = {0, 0, 0, 0}, wlo[4] = {0, 0, 0, 0};
        for (int j = 0; j < 8; ++j) {
            const int ch = 2 * kg + (j >> 2), slot = j & 3;
            float w = 0.0f;
            if (slot < 3) {               // dx = slot-1
                const float* wr = w1w + h * 32 + ch * 4;
                const int iy = q, ix = slot;
                w = wr[1] * SX[iy][ix] + wr[2] * SX[ix][iy] + wr[3] * LP[iy][ix];
                if (q == 1 && slot == 1) w += wr[0];   // ident at center
            }
            const uint32_t hs = bf16rne(w);
            const uint32_t ls = bf16rne(w - bf16tof(hs));
            whi[j >> 1] |= hs << (16 * (j & 1));
            wlo[j >> 1] |= ls << (16 * (j & 1));
        }
        for (int qq = 0; qq < 4; ++qq) {
            wd[q * 512 + t * 4 + qq]       = whi[qq];
            wd[q * 512 + 256 + t * 4 + qq] = wlo[qq];
        }
    }
    uint32_t w2f[4] = {0, 0, 0, 0};
    for (int j = 0; j < 4; ++j) {         // conv2 frag: j>=4 stays zero
        const float v = (h < 8) ? w2w[h * 16 + kg * 4 + j] : 0.0f;
        w2f[j >> 1] |= bf16rne(v) << (16 * (j & 1));
    }
    for (int qq = 0; qq < 4; ++qq) wd[1536 + t * 4 + qq] = w2f[qq];
    if (t < 16) wdf[1792 + t] = w1b[t];
}

__global__ __launch_bounds__(512, 4) void nca_step_kernel(
    const float* __restrict__ x,
    const int*   __restrict__ mask,
    float*       __restrict__ out,
    const float* __restrict__ wdf)
{
    __shared__ uint32_t S32[LDSU];

    // block = one row PAIR; XCD-bijective swizzle (4096 = 8 * 512)
    const int bid = blockIdx.x;
    const int l   = (bid & 7) * 512 + (bid >> 3);
    const int b   = l >> 8;
    const int y0  = (l & 255) << 1;

    const int tid  = threadIdx.x;
    const int lane = tid & 63;
    const int wv   = tid >> 6;            // wave 0..7

    const float* xb = x + (size_t)b * C * HW;
    const int*   mb = mask + (size_t)b * HW;

    // ---- reg-stage: 4096 4-col chunks; thread does 8 (c = tid + 512k) ----
#pragma unroll
    for (int k = 0; k < 8; ++k) {
        const int c     = tid + 512 * k;
        const int rowch = c >> 7;         // 0..31: ch = rowch>>2, rs = rowch&3
        const int m4    = c & 127;        // 4-col chunk within the row
        const int ch    = rowch >> 2, rs = rowch & 3;
        const int grow  = (y0 - 1 + rs) & (H - 1);
        const float* xr = xb + ch * HW + grow * W;
        const float4 v  = *(const float4*)(xr + 4 * m4);
        const float  x4 = xr[(4 * m4 + 4) & (W - 1)];
        uint32_t* rbase = S32 + ch * CH32 + rs * ROW32;
        *(uint2*)(rbase + 2 * m4) = make_uint2(pk2(v.x, v.y), pk2(v.z, v.w));
        rbase[265 + 2 * m4] = pk2(v.y, v.z);       // copyO (odd base: 2x b32)
        rbase[266 + 2 * m4] = pk2(v.w, x4);
    }
    if (tid < 64) {                       // halo slots (from GLOBAL, no dep)
        const int rowch = tid >> 1;
        const int ch = rowch >> 2, rs = rowch & 3;
        const int grow = (y0 - 1 + rs) & (H - 1);
        const float* xr = xb + ch * HW + grow * W;
        uint32_t* rbase = S32 + ch * CH32 + rs * ROW32;
        if (tid & 1) rbase[256] = pk2(xr[0], xr[1]);     // copyE[256] = cols 0,1
        else         rbase[264] = pk2(xr[511], xr[0]);   // copyO[-1] = 511,0
    }
    if (wv < 4) {                         // mask rows via DMA (no conversion)
        const int mr = wv >> 1, hf = wv & 1;
        const int* msrc = mb + (y0 + mr) * W + hf * 256 + lane * 4;
        uint32_t* mdst = S32 + MOFF + mr * 512 + hf * 256;
        __builtin_amdgcn_global_load_lds((as1cp)msrc, (as3p)mdst, 16, 0, 0);
    }

    // per-lane constant fragments (load while stores/DMA fly)
    union { uint4 u; bf16x8 v; } wh0, wl0, wh1, wl1, wh2, wl2, w2U;
    wh0.u = ((const uint4*)wdf)[lane];
    wl0.u = ((const uint4*)wdf)[64 + lane];
    wh1.u = ((const uint4*)wdf)[128 + lane];
    wl1.u = ((const uint4*)wdf)[192 + lane];
    wh2.u = ((const uint4*)wdf)[256 + lane];
    wl2.u = ((const uint4*)wdf)[320 + lane];
    w2U.u = ((const uint4*)wdf)[384 + lane];
    const f32x4 bias4 = ((const f32x4*)(wdf + 1792))[lane >> 4];

    __syncthreads();                      // drains ds_writes + mask DMAs

    // ---- compute: wave wv -> row y0+(wv>>2), groups (wv&3)+4i ----
    const int rel = wv >> 2;
    const int y   = y0 + rel;
    const int grp = lane >> 4;            // lane-group: channels 2grp, 2grp+1
    const int p   = lane & 15;
    const int chA = grp * 2;
    const bool podd = (p & 1) != 0;
    const int px0 = (wv & 3) * 16 + p;
    // u32 idx of pair (px-1,px); pair (px+1,px+2) is ALWAYS e1+1.
    // odd p: copyE banks 8w+0..7; even p: copyO base 264 -> banks 8w+8..15.
    const int e1 = podd ? ((px0 - 1) >> 1) : (264 + (px0 >> 1));
    float* ob = out + (size_t)b * C * HW;

#pragma unroll
    for (int i = 0; i < 8; ++i) {
        const int px = px0 + 64 * i;
        const int o32 = 32 * i;           // u32 offset step per iter

        // B-fragments: 6 paired ds_reads (e1,e1+1 adjacent), zero VALU
        const uint32_t* bA = S32 + chA * CH32 + rel * ROW32;
        const uint32_t* bB = bA + CH32;
        union { uint32_t u[4]; bf16x8 v; } f0 = {{
            bA[e1 + o32],             bA[e1 + 1 + o32],
            bB[e1 + o32],             bB[e1 + 1 + o32]}};
        union { uint32_t u[4]; bf16x8 v; } f1 = {{
            bA[ROW32 + e1 + o32],     bA[ROW32 + e1 + 1 + o32],
            bB[ROW32 + e1 + o32],     bB[ROW32 + e1 + 1 + o32]}};
        union { uint32_t u[4]; bf16x8 v; } f2 = {{
            bA[2 * ROW32 + e1 + o32], bA[2 * ROW32 + e1 + 1 + o32],
            bB[2 * ROW32 + e1 + o32], bB[2 * ROW32 + e1 + 1 + o32]}};

        // conv1 == perception+1x1 fused: 3 chunks x (Whi + Wlo)
        f32x4 acc = bias4;
        acc = __builtin_amdgcn_mfma_f32_16x16x32_bf16(wh0.v, f0.v, acc, 0, 0, 0);
        acc = __builtin_amdgcn_mfma_f32_16x16x32_bf16(wl0.v, f0.v, acc, 0, 0, 0);
        acc = __builtin_amdgcn_mfma_f32_16x16x32_bf16(wh1.v, f1.v, acc, 0, 0, 0);
        acc = __builtin_amdgcn_mfma_f32_16x16x32_bf16(wl1.v, f1.v, acc, 0, 0, 0);
        acc = __builtin_amdgcn_mfma_f32_16x16x32_bf16(wh2.v, f2.v, acc, 0, 0, 0);
        acc = __builtin_amdgcn_mfma_f32_16x16x32_bf16(wl2.v, f2.v, acc, 0, 0, 0);

        // conv2: zero-padded K=32 MFMA (R13/R14-proven path)
        union { uint32_t u[4]; bf16x8 v; } b2 = {{
            pk2(fmaxf(acc[0], 0.f), fmaxf(acc[1], 0.f)),
            pk2(fmaxf(acc[2], 0.f), fmaxf(acc[3], 0.f)), 0, 0}};
        f32x4 d2 = {0.f, 0.f, 0.f, 0.f};
        d2 = __builtin_amdgcn_mfma_f32_16x16x32_bf16(w2U.v, b2.v, d2, 0, 0, 0);

        // epilogue: lanes 0..31 hold och=(lane>>4)*4+r
        if (lane < 32) {
            const float mfv =
                (float)((const int*)(S32 + MOFF))[rel * 512 + px];
            const int och0 = grp * 4;
            float* op = ob + y * W + px;
#pragma unroll
            for (int r = 0; r < 4; ++r) {
                // residual x from bf16 tile: copyE u32 (px>>1), parity half
                const uint32_t vv =
                    S32[(och0 + r) * CH32 + (rel + 1) * ROW32 + (px >> 1)];
                const float xv = __uint_as_float(podd ? (vv & 0xffff0000u)
                                                      : (vv << 16));
                op[(och0 + r) * HW] = fmaf(d2[r], mfv, xv);
            }
        }
    }
}

extern "C" void kernel_launch(void* const* d_in, const int* in_sizes, int n_in,
                              void* d_out, int out_size, void* d_ws, size_t ws_size,
                              hipStream_t stream) {
    const float* x    = (const float*)d_in[0];
    const float* w1w  = (const float*)d_in[1];
    const float* w1b  = (const float*)d_in[2];
    const float* w2w  = (const float*)d_in[3];
    const int*   mask = (const int*)d_in[4];
    float* out = (float*)d_out;
    float* wdf = (float*)d_ws;            // 7.3 KB of fragment scratch

    hipLaunchKernelGGL(repack, dim3(1), dim3(64), 0, stream,
                       w1w, w1b, w2w, wdf);
    hipLaunchKernelGGL(nca_step_kernel, dim3(B * H / 2), dim3(512), 0, stream,
                       x, mask, out, wdf);
}

// Round 22
// 87.359 us; speedup vs baseline: 1.0310x; 1.0310x over previous
//
#include <hip/hip_runtime.h>
#include <hip/hip_bf16.h>
#include <stdint.h>

// Fused NCA step via MATRIX CORES — hybrid: DMA fp32 stage + MFMA-stencil.
// perception(4 fixed 3x3, wrap) -> 1x1 conv 32->16 +b+ReLU -> 1x1 conv 16->8
// -> x + y*mask.
// R22 = the separable best halves of R14 and R21:
//  - STAGE (from R14/R15): fp32 tile via global_load_lds DMA, zero VALU.
//  - COMPUTE (from R21): perception folded into W1 per (dy,dx) (fp32-exact
//    decomposition, hi/lo split -> 6 MFMAs + 1 conv2 MFMA); B-fragments
//    assembled from 4 consecutive fp32 LDS reads + 2 cvt_pk per (ch,row):
//    12 ds_read2_b32 + 12 cvt_pk per iter vs R14's ~90 VALU.
//  - numerics: identical rounding points to R21 (measured absmax 0.03125),
//    residual x from fp32 tile (exact).
// Bank math: CHF==8 (mod 32), chA stride 2*CHF==16 -> groups {0,2}/{1,3} on
// complementary 16-bank halves; every dword access = 2 lanes/bank = free.

constexpr int B = 16, C = 8, H = 512, W = 512, HID = 16;
constexpr int HW = H * W;

// LDS geometry (floats) — R14's exactly. Rows halo-padded:
// data col c at idx c+4; left halo idx3 = col 511; right halo idx516 = col 0.
constexpr int ROWF = 520;            // 2080 B
constexpr int CHF  = 4 * ROWF + 8;   // 2088
constexpr int XTOT = 8 * CHF;        // 16704
constexpr int MOFF = XTOT;           // 2 mask rows (raw int bits)
constexpr int LDSF = XTOT + 2 * 512; // 17728 floats = 70912 B

typedef __attribute__((ext_vector_type(8))) short bf16x8;
typedef __attribute__((ext_vector_type(4))) float f32x4;
typedef const __attribute__((address_space(1))) void* as1cp;
typedef __attribute__((address_space(3))) void* as3p;

__device__ __host__ inline uint32_t bf16rne(float f) {   // low 16 bits
    const uint32_t u = __float_as_uint(f);
    return (u + 0x7fffu + ((u >> 16) & 1u)) >> 16;
}
__device__ __host__ inline float bf16tof(uint32_t hs) {
    union { uint32_t u; float f; } c; c.u = hs << 16; return c.f;
}
// pack {bf16(a) low, bf16(b) high} via HW cvt_pk (RNE)
__device__ inline uint32_t pk2(float a, float b) {
    union { __hip_bfloat162 h; uint32_t u; } r;
    r.h = __float22bfloat162_rn(make_float2(a, b));
    return r.u;
}

// d_ws (u32): [q*512 .. +255] chunk-q W1 hi frag, [+256..511] lo frag
// (q=0,1,2 <-> dy=-1,0,+1); fragment elem j: ch=2*kg+(j>>2), slot=j&3
// (dx=slot-1; slot 3 = pad, weight 0). [1536..1791] W2 frag; [1792..1807] bias.
__global__ void repack(const float* __restrict__ w1w,
                       const float* __restrict__ w1b,
                       const float* __restrict__ w2w,
                       float* __restrict__ wdf) {
    uint32_t* wd = (uint32_t*)wdf;
    const int t = threadIdx.x;
    if (t >= 64) return;
    const int h = t & 15, kg = t >> 4;
    const float SX[3][3] = {{-0.125f, 0.f, 0.125f},
                            {-0.25f,  0.f, 0.25f},
                            {-0.125f, 0.f, 0.125f}};
    const float LP[3][3] = {{0.0625f, 0.125f, 0.0625f},
                            {0.125f, -0.75f,  0.125f},
                            {0.0625f, 0.125f, 0.0625f}};
    for (int q = 0; q < 3; ++q) {         // dy = q-1
        uint32_t whi[4] = {0, 0, 0, 0}, wlo[4] = {0, 0, 0, 0};
        for (int j = 0; j < 8; ++j) {
            const int ch = 2 * kg + (j >> 2), slot = j & 3;
            float w = 0.0f;
            if (slot < 3) {               // dx = slot-1
                const float* wr = w1w + h * 32 + ch * 4;
                const int iy = q, ix = slot;
                w = wr[1] * SX[iy][ix] + wr[2] * SX[ix][iy] + wr[3] * LP[iy][ix];
                if (q == 1 && slot == 1) w += wr[0];   // ident at center
            }
            const uint32_t hs = bf16rne(w);
            const uint32_t ls = bf16rne(w - bf16tof(hs));
            whi[j >> 1] |= hs << (16 * (j & 1));
            wlo[j >> 1] |= ls << (16 * (j & 1));
        }
        for (int qq = 0; qq < 4; ++qq) {
            wd[q * 512 + t * 4 + qq]       = whi[qq];
            wd[q * 512 + 256 + t * 4 + qq] = wlo[qq];
        }
    }
    uint32_t w2f[4] = {0, 0, 0, 0};
    for (int j = 0; j < 4; ++j) {         // conv2 frag: j>=4 stays zero
        const float v = (h < 8) ? w2w[h * 16 + kg * 4 + j] : 0.0f;
        w2f[j >> 1] |= bf16rne(v) << (16 * (j & 1));
    }
    for (int qq = 0; qq < 4; ++qq) wd[1536 + t * 4 + qq] = w2f[qq];
    if (t < 16) wdf[1792 + t] = w1b[t];
}

__global__ __launch_bounds__(512, 4) void nca_step_kernel(
    const float* __restrict__ x,
    const int*   __restrict__ mask,
    float*       __restrict__ out,
    const float* __restrict__ wdf)
{
    __shared__ float S[LDSF];

    // block = one row PAIR; XCD-bijective swizzle (4096 = 8 * 512)
    const int bid = blockIdx.x;
    const int l   = (bid & 7) * 512 + (bid >> 3);
    const int b   = l >> 8;
    const int y0  = (l & 255) << 1;

    const int tid  = threadIdx.x;
    const int lane = tid & 63;
    const int wv   = tid >> 6;            // wave 0..7

    const float* xb = x + (size_t)b * C * HW;
    const int*   mb = mask + (size_t)b * HW;

    // ---- stage (R14/R15 proven): 8 DMAs/wave x-tile + 4 mask DMAs ----
    {
        const int rs   = (wv >> 1) & 3;
        const int hf   = wv & 1;
        const int grow = (y0 - 1 + rs) & (H - 1);
        const int goff = grow * W + hf * 256 + lane * 4;
        const int loff = rs * ROWF + 4 + hf * 256;
#pragma unroll
        for (int ch = 0; ch < 8; ++ch) {
            const float* src = xb + ch * HW + goff;
            float* dst = S + ch * CHF + loff;
            __builtin_amdgcn_global_load_lds((as1cp)src, (as3p)dst, 16, 0, 0);
        }
        if (wv < 4) {                     // mask rows y0,y1 (2 rows x 2 halves)
            const int mr = wv >> 1, h2 = wv & 1;
            const int* msrc = mb + (y0 + mr) * W + h2 * 256 + lane * 4;
            float* mdst = S + MOFF + mr * 512 + h2 * 256;
            __builtin_amdgcn_global_load_lds((as1cp)msrc, (as3p)mdst, 16, 0, 0);
        }
    }

    // per-lane constant fragments (load while DMAs fly)
    union { uint4 u; bf16x8 v; } wh0, wl0, wh1, wl1, wh2, wl2, w2U;
    wh0.u = ((const uint4*)wdf)[lane];
    wl0.u = ((const uint4*)wdf)[64 + lane];
    wh1.u = ((const uint4*)wdf)[128 + lane];
    wl1.u = ((const uint4*)wdf)[192 + lane];
    wh2.u = ((const uint4*)wdf)[256 + lane];
    wl2.u = ((const uint4*)wdf)[320 + lane];
    w2U.u = ((const uint4*)wdf)[384 + lane];
    const f32x4 bias4 = ((const f32x4*)(wdf + 1792))[lane >> 4];

    __syncthreads();                      // drains the DMAs
    if (tid < 64) {                       // halo fill (wrap columns)
        const int r = tid >> 1;
        float* rb = S + (r >> 2) * CHF + (r & 3) * ROWF;
        if (tid & 1) rb[516] = rb[4];     // right halo = col 0
        else         rb[3]   = rb[515];   // left halo  = col 511
    }
    __syncthreads();

    // ---- compute: wave wv -> row y0+(wv>>2), groups (wv&3)+4i ----
    const int rel = wv >> 2;
    const int y   = y0 + rel;
    const int grp = lane >> 4;            // lane-group: channels 2grp, 2grp+1
    const int p   = lane & 15;
    const int chA = grp * 2;
    float* ob = out + (size_t)b * C * HW;

#pragma unroll
    for (int i = 0; i < 8; ++i) {
        const int g  = (wv & 3) + i * 4;
        const int px = g * 16 + p;
        const int ci = px + 3;            // LDS idx of col px-1

        // B-fragments: per (ch,row) read 4 consecutive fp32 (2x ds_read2)
        // then 2 cvt_pk: word(lo)=(px-1,px), word(hi)=(px+1,px+2); the
        // px+2 element lands on the pad slot (weight 0).
        union { uint32_t u[4]; bf16x8 v; } f0, f1, f2;
#pragma unroll
        for (int cc = 0; cc < 2; ++cc) {
            const float* R0 = S + (chA + cc) * CHF + rel * ROWF + ci;
            const float* R1 = R0 + ROWF;
            const float* R2 = R1 + ROWF;
            f0.u[cc * 2]     = pk2(R0[0], R0[1]);
            f0.u[cc * 2 + 1] = pk2(R0[2], R0[3]);
            f1.u[cc * 2]     = pk2(R1[0], R1[1]);
            f1.u[cc * 2 + 1] = pk2(R1[2], R1[3]);
            f2.u[cc * 2]     = pk2(R2[0], R2[1]);
            f2.u[cc * 2 + 1] = pk2(R2[2], R2[3]);
        }

        // conv1 == perception+1x1 fused: 3 row-chunks x (Whi + Wlo)
        f32x4 acc = bias4;
        acc = __builtin_amdgcn_mfma_f32_16x16x32_bf16(wh0.v, f0.v, acc, 0, 0, 0);
        acc = __builtin_amdgcn_mfma_f32_16x16x32_bf16(wl0.v, f0.v, acc, 0, 0, 0);
        acc = __builtin_amdgcn_mfma_f32_16x16x32_bf16(wh1.v, f1.v, acc, 0, 0, 0);
        acc = __builtin_amdgcn_mfma_f32_16x16x32_bf16(wl1.v, f1.v, acc, 0, 0, 0);
        acc = __builtin_amdgcn_mfma_f32_16x16x32_bf16(wh2.v, f2.v, acc, 0, 0, 0);
        acc = __builtin_amdgcn_mfma_f32_16x16x32_bf16(wl2.v, f2.v, acc, 0, 0, 0);

        // conv2: zero-padded K=32 MFMA (R13/R14-proven path)
        union { uint32_t u[4]; bf16x8 v; } b2 = {{
            pk2(fmaxf(acc[0], 0.f), fmaxf(acc[1], 0.f)),
            pk2(fmaxf(acc[2], 0.f), fmaxf(acc[3], 0.f)), 0, 0}};
        f32x4 d2 = {0.f, 0.f, 0.f, 0.f};
        d2 = __builtin_amdgcn_mfma_f32_16x16x32_bf16(w2U.v, b2.v, d2, 0, 0, 0);

        // epilogue: lanes 0..31 hold och=(lane>>4)*4+r (rows 8..15 are pad)
        if (lane < 32) {
            const float mfv =
                (float)((const int*)(S + MOFF))[rel * 512 + px];
            const int och0 = grp * 4;
            float* op = ob + y * W + px;
#pragma unroll
            for (int r = 0; r < 4; ++r) {
                const float xv =
                    S[(och0 + r) * CHF + (rel + 1) * ROWF + 4 + px];
                op[(och0 + r) * HW] = fmaf(d2[r], mfv, xv);
            }
        }
    }
}

extern "C" void kernel_launch(void* const* d_in, const int* in_sizes, int n_in,
                              void* d_out, int out_size, void* d_ws, size_t ws_size,
                              hipStream_t stream) {
    const float* x    = (const float*)d_in[0];
    const float* w1w  = (const float*)d_in[1];
    const float* w1b  = (const float*)d_in[2];
    const float* w2w  = (const float*)d_in[3];
    const int*   mask = (const int*)d_in[4];
    float* out = (float*)d_out;
    float* wdf = (float*)d_ws;            // 7.3 KB of fragment scratch

    hipLaunchKernelGGL(repack, dim3(1), dim3(64), 0, stream,
                       w1w, w1b, w2w, wdf);
    hipLaunchKernelGGL(nca_step_kernel, dim3(B * H / 2), dim3(512), 0, stream,
                       x, mask, out, wdf);
}